// Round 1
// baseline (263.110 us; speedup 1.0000x reference)
//
#include <hip/hip_runtime.h>
#include <hip/hip_bf16.h>

// ContrastiveLoss (SupCon-style), N=4096 rows, K=256 dim, TEMP=0.5.
// loss = mean over same-label off-diag pairs of [log(exp(2*sim_ij) + neg_i) - 2*sim_ij]
//   where neg_i = sum_{lab_j != lab_i} exp(2*sim_ij), sim = rownorm(E) @ rownorm(E)^T.
//
// ws layout (needs ~6.02 MB):
//   [0, 4 MB)          norm_f32   4096x256 f32   (pos-pair dots, fp32 precision)
//   [4 MB, 6 MB)       norm_bf16  4096x256 bf16  (MFMA operand; fits one XCD L2)
//   [6 MB, +16 KB)     neg_sum    4096 f32
//   [+16 KB, +8 B)     acc        {loss_sum, pair_count}
// All ws regions are rewritten/zeroed every call (harness poisons ws with 0xAA).

#define N_ROWS 4096
#define K_DIM  256

typedef __attribute__((ext_vector_type(8))) short short8;     // 8 x bf16 (4 VGPRs)
typedef __attribute__((ext_vector_type(4))) float float4v;    // MFMA C/D

#define NORM_F32_OFF  0
#define NORM_BF16_OFF (N_ROWS * K_DIM * 4)                    // 4194304
#define NEG_OFF       (NORM_BF16_OFF + N_ROWS * K_DIM * 2)    // 6291456
#define ACC_OFF       (NEG_OFF + N_ROWS * 4)                  // 6307840

// ---------------------------------------------------------------------------
// K1: row-normalize (block = one row, 256 threads = 1 elem/thread).
// Also zero-inits neg_sum and accumulators (ws is poisoned each call).
__global__ void normalize_kernel(const float* __restrict__ emb,
                                 float* __restrict__ nf,
                                 __hip_bfloat16* __restrict__ nb,
                                 float* __restrict__ neg_sum,
                                 float* __restrict__ acc) {
    int row = blockIdx.x;
    int t   = threadIdx.x;
    float x = emb[row * K_DIM + t];
    float s = x * x;
    #pragma unroll
    for (int off = 32; off > 0; off >>= 1) s += __shfl_down(s, off, 64);
    __shared__ float red[4];
    int wave = t >> 6, lane = t & 63;
    if (lane == 0) red[wave] = s;
    __syncthreads();
    float tot = red[0] + red[1] + red[2] + red[3];
    float scale = 1.0f / fmaxf(sqrtf(tot), 1e-12f);
    float v = x * scale;
    nf[row * K_DIM + t] = v;
    nb[row * K_DIM + t] = __float2bfloat16(v);
    if (row < N_ROWS / 256) neg_sum[row * 256 + t] = 0.0f;  // 16*256 = 4096
    if (row == 0 && t < 2) acc[t] = 0.0f;
}

// ---------------------------------------------------------------------------
// K2: neg_sum via bf16 MFMA. One wave owns a 16-row strip x 256-col segment.
// A/B frag for mfma_f32_16x16x32_bf16: lane reads row (base + (lane&15)),
// k = (lane>>4)*8 + j  (8 contiguous bf16 = 16 B).  C/D: col = lane&15,
// row = (lane>>4)*4 + reg  [measured: learn_hip m89/m91].
// Grid: 1024 blocks x 256 thr = 4096 waves = 256 strips x 16 col-segments.
__global__ void negsum_kernel(const __hip_bfloat16* __restrict__ nb,
                              const int* __restrict__ labels,
                              float* __restrict__ neg_sum) {
    int wid   = (blockIdx.x << 2) + (threadIdx.x >> 6);
    int lane  = threadIdx.x & 63;
    int row16 = lane & 15, quad = lane >> 4;
    int istrip = wid >> 4;          // 0..255
    int jseg   = wid & 15;          // 0..15
    int i0 = istrip * 16;
    const short* nbs = reinterpret_cast<const short*>(nb);

    short8 afrag[8];
    {
        const short* ap = nbs + (i0 + row16) * K_DIM + quad * 8;
        #pragma unroll
        for (int c = 0; c < 8; ++c)
            afrag[c] = *reinterpret_cast<const short8*>(ap + c * 32);
    }
    int labi[4];
    #pragma unroll
    for (int r = 0; r < 4; ++r) labi[r] = labels[i0 + quad * 4 + r];

    float negacc[4] = {0.f, 0.f, 0.f, 0.f};
    int jbase = jseg * 256;
    for (int jt = 0; jt < 16; ++jt) {
        int j0 = jbase + jt * 16;
        const short* bp = nbs + (j0 + row16) * K_DIM + quad * 8;
        float4v accf = {0.f, 0.f, 0.f, 0.f};
        #pragma unroll
        for (int c = 0; c < 8; ++c) {
            short8 bfrag = *reinterpret_cast<const short8*>(bp + c * 32);
            accf = __builtin_amdgcn_mfma_f32_16x16x32_bf16(afrag[c], bfrag, accf, 0, 0, 0);
        }
        int labj = labels[j0 + row16];   // col = lane&15
        #pragma unroll
        for (int r = 0; r < 4; ++r) {
            float e = __expf(2.0f * accf[r]);
            negacc[r] += (labj != labi[r]) ? e : 0.0f;  // diagonal auto-excluded (same label)
        }
    }
    // reduce over the 16 lanes of each quad (cols), then one atomic per row
    #pragma unroll
    for (int r = 0; r < 4; ++r) {
        float v = negacc[r];
        v += __shfl_xor(v, 1); v += __shfl_xor(v, 2);
        v += __shfl_xor(v, 4); v += __shfl_xor(v, 8);
        if (row16 == 0) atomicAdd(&neg_sum[i0 + quad * 4 + r], v);
    }
}

// ---------------------------------------------------------------------------
// K3: sparse same-label pairs (~28k total). Block = one row i; threads scan j,
// matching threads do an fp32 dot (L2-resident) and accumulate loss + count.
__global__ void posloss_kernel(const float* __restrict__ nf,
                               const int* __restrict__ labels,
                               const float* __restrict__ neg_sum,
                               float* __restrict__ acc) {
    int i = blockIdx.x;
    int li = labels[i];
    float nsum = neg_sum[i];
    const float* arow = nf + i * K_DIM;
    float lsum = 0.f, cnt = 0.f;
    for (int j = threadIdx.x; j < N_ROWS; j += 256) {
        if (j != i && labels[j] == li) {
            const float* brow = nf + j * K_DIM;
            float d = 0.f;
            #pragma unroll 8
            for (int k = 0; k < K_DIM; ++k) d = fmaf(arow[k], brow[k], d);
            float t2 = 2.0f * d;
            lsum += logf(__expf(t2) + nsum) - t2;
            cnt  += 1.0f;
        }
    }
    #pragma unroll
    for (int off = 32; off > 0; off >>= 1) {
        lsum += __shfl_down(lsum, off, 64);
        cnt  += __shfl_down(cnt,  off, 64);
    }
    __shared__ float sl[4], sc[4];
    int wave = threadIdx.x >> 6, lane = threadIdx.x & 63;
    if (lane == 0) { sl[wave] = lsum; sc[wave] = cnt; }
    __syncthreads();
    if (threadIdx.x == 0) {
        atomicAdd(&acc[0], sl[0] + sl[1] + sl[2] + sl[3]);
        atomicAdd(&acc[1], sc[0] + sc[1] + sc[2] + sc[3]);
    }
}

// ---------------------------------------------------------------------------
__global__ void finalize_kernel(const float* __restrict__ acc, float* __restrict__ out) {
    if (threadIdx.x == 0) out[0] = acc[0] / acc[1];
}

// ---------------------------------------------------------------------------
extern "C" void kernel_launch(void* const* d_in, const int* in_sizes, int n_in,
                              void* d_out, int out_size, void* d_ws, size_t ws_size,
                              hipStream_t stream) {
    const float* emb    = (const float*)d_in[0];
    const int*   labels = (const int*)d_in[1];
    float* out = (float*)d_out;
    char*  ws  = (char*)d_ws;

    float*          nf  = (float*)(ws + NORM_F32_OFF);
    __hip_bfloat16* nbf = (__hip_bfloat16*)(ws + NORM_BF16_OFF);
    float*          neg = (float*)(ws + NEG_OFF);
    float*          acc = (float*)(ws + ACC_OFF);

    normalize_kernel<<<N_ROWS, 256, 0, stream>>>(emb, nf, nbf, neg, acc);
    negsum_kernel<<<1024, 256, 0, stream>>>(nbf, labels, neg);
    posloss_kernel<<<N_ROWS, 256, 0, stream>>>(nf, labels, neg, acc);
    finalize_kernel<<<1, 64, 0, stream>>>(acc, out);
}

// Round 2
// 154.405 us; speedup vs baseline: 1.7040x; 1.7040x over previous
//
#include <hip/hip_runtime.h>
#include <hip/hip_bf16.h>

// ContrastiveLoss (SupCon-style), N=4096 rows, K=256 dim, TEMP=0.5.
// loss = mean over same-label off-diag pairs of [log(neg_i + e_ij) - t2_ij],
//   t2_ij = 2*sim_ij, e_ij = exp(t2_ij), neg_i = sum_{lab_j != lab_i} e_ij.
// Since e_ij <= e^2 ~ 7.4 and neg_i >= ~550, expand per-pair log around neg_i:
//   log(neg_i + e) = log(neg_i) + e/neg_i - e^2/(2 neg_i^2) + O(8e-6)
// -> everything reduces to 5 per-row sums computed inside the MFMA pass:
//   neg_i, pexp_i = S e, pexp2_i = S e^2, pt2_i = S t2, pcnt_i  (S over pos pairs)
// Final: loss = S_i [cnt*log(neg) + pexp/neg - pexp2/(2 neg^2) - pt2] / S_i cnt.
//
// ws layout (~2.1 MB):
//   [0, 2 MB)      norm_bf16  4096x256 bf16 (MFMA operand; L2-resident)
//   [2 MB, +80 KB) stats      5 x 4096 f32  (neg, pexp, pexp2, pt2, pcnt)

#define N_ROWS 4096
#define K_DIM  256
#define NJSEG  32          // j split into 32 segments of 128 cols (8 16-tiles)

typedef __attribute__((ext_vector_type(8))) short short8;     // 8 x bf16
typedef __attribute__((ext_vector_type(4))) float float4v;    // MFMA C/D

#define NB_OFF    0
#define STATS_OFF (N_ROWS * K_DIM * 2)   // 2 MB

// ---------------------------------------------------------------------------
// K1: row-normalize to bf16 (block = one row). Also zero the 5 stat arrays
// (5*4096 = 20480 floats = 80 blocks x 256).
__global__ void normalize_kernel(const float* __restrict__ emb,
                                 __hip_bfloat16* __restrict__ nb,
                                 float* __restrict__ stats) {
    int row = blockIdx.x;
    int t   = threadIdx.x;
    float x = emb[row * K_DIM + t];
    float s = x * x;
    #pragma unroll
    for (int off = 32; off > 0; off >>= 1) s += __shfl_down(s, off, 64);
    __shared__ float red[4];
    int wave = t >> 6, lane = t & 63;
    if (lane == 0) red[wave] = s;
    __syncthreads();
    float tot = red[0] + red[1] + red[2] + red[3];
    float scale = 1.0f / fmaxf(sqrtf(tot), 1e-12f);
    nb[row * K_DIM + t] = __float2bfloat16(x * scale);
    if (row < 80) stats[row * 256 + t] = 0.0f;
}

// ---------------------------------------------------------------------------
// K2: fused sim/exp/stats pass via bf16 MFMA (16x16x32).
// Wave = 16-row strip x 128-col segment. The 4 waves of a block share the SAME
// j-segment (same B stream -> L1 reuse) and take 4 consecutive i-strips.
// Grid: 2048 blocks x 4 waves = 8192 waves = 256 istrips x 32 jsegs.
// Frags: A/B lane reads 8 contiguous k of row (lane&15), k-base (lane>>4)*8.
// C/D: col = lane&15, row = (lane>>4)*4 + reg  [learn_hip m89/m91].
__global__ void negsum_kernel(const __hip_bfloat16* __restrict__ nb,
                              const int* __restrict__ labels,
                              float* __restrict__ neg,
                              float* __restrict__ pexp,
                              float* __restrict__ pexp2,
                              float* __restrict__ pt2,
                              float* __restrict__ pcnt) {
    int w     = threadIdx.x >> 6;
    int lane  = threadIdx.x & 63;
    int row16 = lane & 15, quad = lane >> 4;
    int jseg   = blockIdx.x & (NJSEG - 1);
    int istrip = (blockIdx.x >> 5) * 4 + w;      // 0..255
    int i0 = istrip * 16;
    const short* nbs = reinterpret_cast<const short*>(nb);

    short8 afrag[8];
    {
        const short* ap = nbs + (i0 + row16) * K_DIM + quad * 8;
        #pragma unroll
        for (int c = 0; c < 8; ++c)
            afrag[c] = *reinterpret_cast<const short8*>(ap + c * 32);
    }
    int labi[4], irow[4];
    #pragma unroll
    for (int r = 0; r < 4; ++r) {
        irow[r] = i0 + quad * 4 + r;
        labi[r] = labels[irow[r]];
    }

    float nacc[4] = {0,0,0,0};
    float pe[4]   = {0,0,0,0};
    float pe2[4]  = {0,0,0,0};
    float ptt[4]  = {0,0,0,0};
    float pc[4]   = {0,0,0,0};

    int jbase = jseg * 128;
    #pragma unroll 2
    for (int jt = 0; jt < 8; ++jt) {
        int j0 = jbase + jt * 16;
        const short* bp = nbs + (j0 + row16) * K_DIM + quad * 8;
        float4v accf = {0.f, 0.f, 0.f, 0.f};
        #pragma unroll
        for (int c = 0; c < 8; ++c) {
            short8 bfrag = *reinterpret_cast<const short8*>(bp + c * 32);
            accf = __builtin_amdgcn_mfma_f32_16x16x32_bf16(afrag[c], bfrag, accf, 0, 0, 0);
        }
        int j    = j0 + row16;     // this lane's column index
        int labj = labels[j];
        #pragma unroll
        for (int r = 0; r < 4; ++r) {
            float t2 = 2.0f * accf[r];
            float e  = __expf(t2);
            bool same = (labj == labi[r]);
            float mpos = (same && j != irow[r]) ? 1.0f : 0.0f;  // pos pair mask
            nacc[r] += same ? 0.0f : e;
            pe[r]  += mpos * e;
            pe2[r] += mpos * e * e;
            ptt[r] += mpos * t2;
            pc[r]  += mpos;
        }
    }

    // reduce over the 16 column-lanes of each quad, one atomic set per row
    #pragma unroll
    for (int r = 0; r < 4; ++r) {
        float v0 = nacc[r], v1 = pe[r], v2 = pe2[r], v3 = ptt[r], v4 = pc[r];
        #pragma unroll
        for (int m = 1; m < 16; m <<= 1) {
            v0 += __shfl_xor(v0, m); v1 += __shfl_xor(v1, m);
            v2 += __shfl_xor(v2, m); v3 += __shfl_xor(v3, m);
            v4 += __shfl_xor(v4, m);
        }
        if (row16 == 0) {
            atomicAdd(&neg[irow[r]], v0);
            if (v4 > 0.0f) {       // most (row, jseg) groups have no pos pairs
                atomicAdd(&pexp[irow[r]],  v1);
                atomicAdd(&pexp2[irow[r]], v2);
                atomicAdd(&pt2[irow[r]],   v3);
                atomicAdd(&pcnt[irow[r]],  v4);
            }
        }
    }
}

// ---------------------------------------------------------------------------
// K3: single-block finalize: per-row closed form, block reduce, write scalar.
__global__ void finalize_kernel(const float* __restrict__ neg,
                                const float* __restrict__ pexp,
                                const float* __restrict__ pexp2,
                                const float* __restrict__ pt2,
                                const float* __restrict__ pcnt,
                                float* __restrict__ out) {
    float lsum = 0.f, csum = 0.f;
    for (int i = threadIdx.x; i < N_ROWS; i += 256) {
        float c = pcnt[i];
        if (c > 0.f) {
            float n = neg[i];
            float invn = 1.0f / n;
            lsum += c * logf(n) + pexp[i] * invn
                    - 0.5f * pexp2[i] * invn * invn - pt2[i];
            csum += c;
        }
    }
    #pragma unroll
    for (int off = 32; off > 0; off >>= 1) {
        lsum += __shfl_down(lsum, off, 64);
        csum += __shfl_down(csum, off, 64);
    }
    __shared__ float sl[4], sc[4];
    int wave = threadIdx.x >> 6, lane = threadIdx.x & 63;
    if (lane == 0) { sl[wave] = lsum; sc[wave] = csum; }
    __syncthreads();
    if (threadIdx.x == 0)
        out[0] = (sl[0] + sl[1] + sl[2] + sl[3]) / (sc[0] + sc[1] + sc[2] + sc[3]);
}

// ---------------------------------------------------------------------------
extern "C" void kernel_launch(void* const* d_in, const int* in_sizes, int n_in,
                              void* d_out, int out_size, void* d_ws, size_t ws_size,
                              hipStream_t stream) {
    const float* emb    = (const float*)d_in[0];
    const int*   labels = (const int*)d_in[1];
    float* out = (float*)d_out;
    char*  ws  = (char*)d_ws;

    __hip_bfloat16* nb    = (__hip_bfloat16*)(ws + NB_OFF);
    float*          stats = (float*)(ws + STATS_OFF);
    float* neg   = stats;
    float* pexp  = stats + N_ROWS;
    float* pexp2 = stats + 2 * N_ROWS;
    float* pt2   = stats + 3 * N_ROWS;
    float* pcnt  = stats + 4 * N_ROWS;

    normalize_kernel<<<N_ROWS, 256, 0, stream>>>(emb, nb, stats);
    negsum_kernel<<<2048, 256, 0, stream>>>(nb, labels, neg, pexp, pexp2, pt2, pcnt);
    finalize_kernel<<<1, 256, 0, stream>>>(neg, pexp, pexp2, pt2, pcnt, out);
}

// Round 3
// 106.945 us; speedup vs baseline: 2.4602x; 1.4438x over previous
//
#include <hip/hip_runtime.h>
#include <hip/hip_bf16.h>

// ContrastiveLoss (SupCon-style), N=4096 rows, K=256 dim, TEMP=0.5.
// loss = mean over same-label off-diag pairs of [log(neg_i + e_ij) - t2_ij],
//   t2_ij = 2*sim_ij, e_ij = exp(t2_ij), neg_i = sum_{lab_j != lab_i} e_ij.
// e_ij <= e^2 ~ 7.4, neg_i >= ~550  ->  per-pair log expands to per-row sums:
//   log(neg_i + e) = log(neg_i) + e/neg_i - e^2/(2 neg_i^2) + O(8e-6)
// so the MFMA pass only accumulates 5 per-row scalars.
//
// R3 change (theory: R2 negsum was gather-issue-bound — every frag load hit 16
// disjoint 64B segments, all pipes <10% busy): store normalized bf16 directly
// in MFMA FRAGMENT ORDER so every A/B frag load is one contiguous 1KB segment.
//   P[((tile*8 + c)*64 + lane)*8 + j] = norm[16*tile + (lane&15)]
//                                           [(lane>>4)*8 + c*32 + j]
// (A and B share this layout since sim = N @ N^T.)
//
// ws layout (~2.1 MB):
//   [0, 2 MB)      packed bf16 frags (L2-resident)
//   [2 MB, +80 KB) stats: 5 x 4096 f32 (neg, pexp, pexp2, pt2, pcnt)

#define N_ROWS 4096
#define K_DIM  256
#define NJSEG  32          // j split into 32 segments of 128 cols (8 16-tiles)

typedef __attribute__((ext_vector_type(8))) short short8;     // 8 x bf16
typedef __attribute__((ext_vector_type(4))) float float4v;    // MFMA C/D

#define PK_OFF    0
#define STATS_OFF (N_ROWS * K_DIM * 2)   // 2 MB

// ---------------------------------------------------------------------------
// K1: row-normalize (block = one row, thread t = element k), store straight
// into packed-fragment order. Also zero the 5 stat arrays (80 x 256 floats).
__global__ void normalize_kernel(const float* __restrict__ emb,
                                 short* __restrict__ pk,
                                 float* __restrict__ stats) {
    int row = blockIdx.x;
    int k   = threadIdx.x;
    float x = emb[row * K_DIM + k];
    float s = x * x;
    #pragma unroll
    for (int off = 32; off > 0; off >>= 1) s += __shfl_down(s, off, 64);
    __shared__ float red[4];
    int wave = k >> 6, lane = k & 63;
    if (lane == 0) red[wave] = s;
    __syncthreads();
    float tot = red[0] + red[1] + red[2] + red[3];
    float scale = 1.0f / fmaxf(sqrtf(tot), 1e-12f);
    __hip_bfloat16 v = __float2bfloat16(x * scale);
    // packed index (shorts): tile=row>>4, c=k>>5, quad=(k>>3)&3, r16=row&15, j=k&7
    int idx = ((row >> 4) << 12) + ((k >> 5) << 9) + (((k >> 3) & 3) << 7)
              + ((row & 15) << 3) + (k & 7);
    pk[idx] = *reinterpret_cast<short*>(&v);
    if (row < 80) stats[row * 256 + k] = 0.0f;
}

// ---------------------------------------------------------------------------
// K2: fused sim/exp/stats pass via bf16 MFMA (16x16x32), packed-frag operands.
// Wave = 16-row strip x 128-col segment; 4 waves/block share the j-segment.
// Grid: 2048 blocks x 4 waves = 8192 waves = 256 istrips x 32 jsegs.
// Every frag load: P + ((tile*8+c)<<9) + lane*8  -> one 1KB coalesced segment.
// C/D: col = lane&15, row = (lane>>4)*4 + reg  [learn_hip m89/m91].
__global__ void negsum_kernel(const short* __restrict__ pk,
                              const int* __restrict__ labels,
                              float* __restrict__ neg,
                              float* __restrict__ pexp,
                              float* __restrict__ pexp2,
                              float* __restrict__ pt2,
                              float* __restrict__ pcnt) {
    int w     = threadIdx.x >> 6;
    int lane  = threadIdx.x & 63;
    int row16 = lane & 15, quad = lane >> 4;
    int jseg   = blockIdx.x & (NJSEG - 1);
    int istrip = (blockIdx.x >> 5) * 4 + w;      // 0..255
    int i0 = istrip * 16;

    short8 afrag[8];
    {
        const short* ap = pk + (istrip << 12) + lane * 8;
        #pragma unroll
        for (int c = 0; c < 8; ++c)
            afrag[c] = *reinterpret_cast<const short8*>(ap + (c << 9));
    }
    int labi[4], irow[4];
    #pragma unroll
    for (int r = 0; r < 4; ++r) {
        irow[r] = i0 + quad * 4 + r;
        labi[r] = labels[irow[r]];
    }

    float nacc[4] = {0,0,0,0};
    float pe[4]   = {0,0,0,0};
    float pe2[4]  = {0,0,0,0};
    float ptt[4]  = {0,0,0,0};
    float pc[4]   = {0,0,0,0};

    int jt0 = jseg * 8;                          // first 16-col tile index
    #pragma unroll 2
    for (int jt = 0; jt < 8; ++jt) {
        const short* bp = pk + ((jt0 + jt) << 12) + lane * 8;
        float4v accf = {0.f, 0.f, 0.f, 0.f};
        #pragma unroll
        for (int c = 0; c < 8; ++c) {
            short8 bfrag = *reinterpret_cast<const short8*>(bp + (c << 9));
            accf = __builtin_amdgcn_mfma_f32_16x16x32_bf16(afrag[c], bfrag, accf, 0, 0, 0);
        }
        int j    = (jt0 + jt) * 16 + row16;      // this lane's column index
        int labj = labels[j];
        #pragma unroll
        for (int r = 0; r < 4; ++r) {
            float t2 = 2.0f * accf[r];
            float e  = __expf(t2);
            bool same = (labj == labi[r]);
            float mpos = (same && j != irow[r]) ? 1.0f : 0.0f;
            nacc[r] += same ? 0.0f : e;
            pe[r]  += mpos * e;
            pe2[r] += mpos * e * e;
            ptt[r] += mpos * t2;
            pc[r]  += mpos;
        }
    }

    // reduce over the 16 column-lanes of each quad, one atomic set per row
    #pragma unroll
    for (int r = 0; r < 4; ++r) {
        float v0 = nacc[r], v1 = pe[r], v2 = pe2[r], v3 = ptt[r], v4 = pc[r];
        #pragma unroll
        for (int m = 1; m < 16; m <<= 1) {
            v0 += __shfl_xor(v0, m); v1 += __shfl_xor(v1, m);
            v2 += __shfl_xor(v2, m); v3 += __shfl_xor(v3, m);
            v4 += __shfl_xor(v4, m);
        }
        if (row16 == 0) {
            atomicAdd(&neg[irow[r]], v0);
            if (v4 > 0.0f) {       // most (row, jseg) groups have no pos pairs
                atomicAdd(&pexp[irow[r]],  v1);
                atomicAdd(&pexp2[irow[r]], v2);
                atomicAdd(&pt2[irow[r]],   v3);
                atomicAdd(&pcnt[irow[r]],  v4);
            }
        }
    }
}

// ---------------------------------------------------------------------------
// K3: single-block finalize: per-row closed form, block reduce, write scalar.
__global__ void finalize_kernel(const float* __restrict__ neg,
                                const float* __restrict__ pexp,
                                const float* __restrict__ pexp2,
                                const float* __restrict__ pt2,
                                const float* __restrict__ pcnt,
                                float* __restrict__ out) {
    float lsum = 0.f, csum = 0.f;
    for (int i = threadIdx.x; i < N_ROWS; i += 256) {
        float c = pcnt[i];
        if (c > 0.f) {
            float n = neg[i];
            float invn = 1.0f / n;
            lsum += c * logf(n) + pexp[i] * invn
                    - 0.5f * pexp2[i] * invn * invn - pt2[i];
            csum += c;
        }
    }
    #pragma unroll
    for (int off = 32; off > 0; off >>= 1) {
        lsum += __shfl_down(lsum, off, 64);
        csum += __shfl_down(csum, off, 64);
    }
    __shared__ float sl[4], sc[4];
    int wave = threadIdx.x >> 6, lane = threadIdx.x & 63;
    if (lane == 0) { sl[wave] = lsum; sc[wave] = csum; }
    __syncthreads();
    if (threadIdx.x == 0)
        out[0] = (sl[0] + sl[1] + sl[2] + sl[3]) / (sc[0] + sc[1] + sc[2] + sc[3]);
}

// ---------------------------------------------------------------------------
extern "C" void kernel_launch(void* const* d_in, const int* in_sizes, int n_in,
                              void* d_out, int out_size, void* d_ws, size_t ws_size,
                              hipStream_t stream) {
    const float* emb    = (const float*)d_in[0];
    const int*   labels = (const int*)d_in[1];
    float* out = (float*)d_out;
    char*  ws  = (char*)d_ws;

    short* pk    = (short*)(ws + PK_OFF);
    float* stats = (float*)(ws + STATS_OFF);
    float* neg   = stats;
    float* pexp  = stats + N_ROWS;
    float* pexp2 = stats + 2 * N_ROWS;
    float* pt2   = stats + 3 * N_ROWS;
    float* pcnt  = stats + 4 * N_ROWS;

    normalize_kernel<<<N_ROWS, 256, 0, stream>>>(emb, pk, stats);
    negsum_kernel<<<2048, 256, 0, stream>>>(pk, labels, neg, pexp, pexp2, pt2, pcnt);
    finalize_kernel<<<1, 256, 0, stream>>>(neg, pexp, pexp2, pt2, pcnt, out);
}